// Round 1
// baseline (917.979 us; speedup 1.0000x reference)
//
#include <hip/hip_runtime.h>
#include <hip/hip_bf16.h>

#define NN 50000
#define NE 500000

typedef __attribute__((ext_vector_type(4))) float f32x4;
typedef __attribute__((ext_vector_type(8))) short bf16x8;
typedef unsigned short u16;

#define LDK 136    // 128 + 8 pad, in u16 units (272 B row stride -> 2-way LDS conflicts only)
#define LDK2 264   // 256 + 8 pad

#define MFMA16(a, b, c) __builtin_amdgcn_mfma_f32_16x16x32_bf16((a), (b), (c), 0, 0, 0)

__device__ __forceinline__ float bf2f(u16 u) {
    union { unsigned int i; float f; } v; v.i = ((unsigned int)u) << 16; return v.f;
}
__device__ __forceinline__ u16 f2bf(float f) {
    union { float f; unsigned int i; } v; v.f = f;
    return (u16)((v.i + 0x7fffu + ((v.i >> 16) & 1u)) >> 16);  // RTNE
}

// ---------------------------------------------------------------------------
// prep: transpose + bf16-convert all weight blocks into ws
//   W1at [128][128] : W1at[j][k] = eW1[k][j]            (edges part of eW1)
//   eW2t [128][128] : eW2t[j][k] = eW2[k][j]
//   Wbct [256][128] : j<128 -> eW1[(128+k)][j] (sent) ; j>=128 -> eW1[(256+k)][j-128] (recv)
//   nW1t [128][256] : nW1t[j][k] = nW1[k][j]
//   nW2t [128][128] : nW2t[j][k] = nW2[k][j]
// ---------------------------------------------------------------------------
__global__ void prep_w(const float* __restrict__ eW1, const float* __restrict__ eW2,
                       const float* __restrict__ nW1, const float* __restrict__ nW2,
                       u16* __restrict__ W1at, u16* __restrict__ eW2t, u16* __restrict__ Wbct,
                       u16* __restrict__ nW1t, u16* __restrict__ nW2t) {
    int idx = blockIdx.x * blockDim.x + threadIdx.x;
    if (idx < 16384) { int j = idx >> 7, k = idx & 127; W1at[j * 128 + k] = f2bf(eW1[k * 128 + j]); return; }
    idx -= 16384;
    if (idx < 16384) { int j = idx >> 7, k = idx & 127; eW2t[j * 128 + k] = f2bf(eW2[k * 128 + j]); return; }
    idx -= 16384;
    if (idx < 32768) {
        int j = idx >> 7, k = idx & 127;
        float v = (j < 128) ? eW1[(128 + k) * 128 + j] : eW1[(256 + k) * 128 + (j - 128)];
        Wbct[j * 128 + k] = f2bf(v); return;
    }
    idx -= 32768;
    if (idx < 32768) { int j = idx >> 8, k = idx & 255; nW1t[j * 256 + k] = f2bf(nW1[k * 128 + j]); return; }
    idx -= 32768;
    if (idx < 16384) { int j = idx >> 7, k = idx & 127; nW2t[j * 128 + k] = f2bf(nW2[k * 128 + j]); return; }
}

// ---------------------------------------------------------------------------
// node_pq: PQw[n][0:128] = nodes[n] @ W1b ; PQw[n][128:256] = nodes[n] @ W1c   (bf16)
// 64-node tiles, 8 waves, each wave owns 32 of the 256 output cols.
// ---------------------------------------------------------------------------
__global__ __launch_bounds__(512)
void node_pq(const float* __restrict__ nodes, const u16* __restrict__ Wbct,
             u16* __restrict__ PQw) {
    __shared__ u16 Xs[64 * LDK];
    __shared__ u16 Ws[256 * LDK];
    const int tid = threadIdx.x;
    const int n0 = blockIdx.x * 64;
    const int nvalid = min(64, NN - n0);

    for (int idx = tid; idx < 64 * 32; idx += 512) {
        int row = idx >> 5, c4 = idx & 31;
        int nd = n0 + row; if (nd >= NN) nd = NN - 1;
        float4 v = *(const float4*)(nodes + (size_t)nd * 128 + c4 * 4);
        ushort4 u; u.x = f2bf(v.x); u.y = f2bf(v.y); u.z = f2bf(v.z); u.w = f2bf(v.w);
        *(ushort4*)(Xs + row * LDK + c4 * 4) = u;
    }
    for (int idx = tid; idx < 256 * 16; idx += 512) {
        int row = idx >> 4, c = idx & 15;
        *(int4*)(Ws + row * LDK + c * 8) = *(const int4*)(Wbct + row * 128 + c * 8);
    }
    __syncthreads();

    const int lane = tid & 63;
    const int w = tid >> 6;
    const int cb = w * 32;
    const int l15 = lane & 15, l4 = lane >> 4;

    f32x4 acc[4][2] = {};
#pragma unroll
    for (int k0 = 0; k0 < 128; k0 += 32) {
        bf16x8 a[4], b[2];
#pragma unroll
        for (int f = 0; f < 4; ++f)
            a[f] = *(const bf16x8*)(Xs + (f * 16 + l15) * LDK + k0 + l4 * 8);
#pragma unroll
        for (int f = 0; f < 2; ++f)
            b[f] = *(const bf16x8*)(Ws + (cb + f * 16 + l15) * LDK + k0 + l4 * 8);
#pragma unroll
        for (int i = 0; i < 4; ++i)
#pragma unroll
            for (int j = 0; j < 2; ++j)
                acc[i][j] = MFMA16(a[i], b[j], acc[i][j]);
    }
#pragma unroll
    for (int i = 0; i < 4; ++i)
#pragma unroll
        for (int j = 0; j < 2; ++j) {
            int n = cb + j * 16 + l15;
#pragma unroll
            for (int v = 0; v < 4; ++v) {
                int m = i * 16 + l4 * 4 + v;
                if (m < nvalid) PQw[(size_t)(n0 + m) * 256 + n] = f2bf(acc[i][j][v]);
            }
        }
}

// ---------------------------------------------------------------------------
// edge_mlp: fused edge MLP (both layers) + residual write + atomic scatter
// h   = relu(edges@W1a + P[send] + Q[recv] + eb1)
// upd = h@eW2 + eb2
// edges_out = edges + mult*upd ; adj[recv] += upd
// 64-edge tiles, 8 waves as 2(M)x4(N) of 32x32.
// ---------------------------------------------------------------------------
__global__ __launch_bounds__(512)
void edge_mlp(const float* __restrict__ edges,
              const int* __restrict__ recv, const int* __restrict__ send,
              const u16* __restrict__ PQw,
              const u16* __restrict__ W1at, const u16* __restrict__ W2t,
              const float* __restrict__ eb1, const float* __restrict__ eb2,
              const float* __restrict__ rm_w,
              float* __restrict__ edges_out, float* __restrict__ adj) {
    __shared__ u16 Xs[64 * LDK];
    __shared__ u16 PQs[64 * LDK2];
    __shared__ u16 W1s[128 * LDK];
    __shared__ u16 W2s[128 * LDK];
    __shared__ u16 Hs[64 * LDK];
    __shared__ int Rs[64];

    const int tid = threadIdx.x;
    const int e0 = blockIdx.x * 64;
    const int nvalid = min(64, NE - e0);
    const float mult = log1pf(expf(rm_w[0]));

    for (int idx = tid; idx < 64 * 32; idx += 512) {   // stage edges tile (fp32 -> bf16)
        int row = idx >> 5, c4 = idx & 31;
        int e = e0 + row; if (e >= NE) e = NE - 1;
        float4 v = *(const float4*)(edges + (size_t)e * 128 + c4 * 4);
        ushort4 u; u.x = f2bf(v.x); u.y = f2bf(v.y); u.z = f2bf(v.z); u.w = f2bf(v.w);
        *(ushort4*)(Xs + row * LDK + c4 * 4) = u;
    }
    if (tid < 64) {
        int e = e0 + tid; if (e >= NE) e = NE - 1;
        Rs[tid] = recv[e];
    }
    for (int idx = tid; idx < 64 * 32; idx += 512) {   // gather P[send] | Q[recv] rows (bf16)
        int row = idx >> 5, half = (idx >> 4) & 1, c = idx & 15;
        int e = e0 + row; if (e >= NE) e = NE - 1;
        int node = half ? recv[e] : send[e];
        int4 v = *(const int4*)(PQw + (size_t)node * 256 + half * 128 + c * 8);
        *(int4*)(PQs + row * LDK2 + half * 128 + c * 8) = v;
    }
    for (int idx = tid; idx < 128 * 16; idx += 512) {  // stage both weight matrices
        int row = idx >> 4, c = idx & 15;
        *(int4*)(W1s + row * LDK + c * 8) = *(const int4*)(W1at + row * 128 + c * 8);
        *(int4*)(W2s + row * LDK + c * 8) = *(const int4*)(W2t + row * 128 + c * 8);
    }
    __syncthreads();

    const int lane = tid & 63;
    const int w = tid >> 6;
    const int rb = (w >> 2) * 32, cb = (w & 3) * 32;
    const int l15 = lane & 15, l4 = lane >> 4;

    f32x4 acc[2][2] = {};
#pragma unroll
    for (int k0 = 0; k0 < 128; k0 += 32) {
        bf16x8 a[2], b[2];
#pragma unroll
        for (int f = 0; f < 2; ++f) {
            a[f] = *(const bf16x8*)(Xs + (rb + f * 16 + l15) * LDK + k0 + l4 * 8);
            b[f] = *(const bf16x8*)(W1s + (cb + f * 16 + l15) * LDK + k0 + l4 * 8);
        }
#pragma unroll
        for (int i = 0; i < 2; ++i)
#pragma unroll
            for (int j = 0; j < 2; ++j)
                acc[i][j] = MFMA16(a[i], b[j], acc[i][j]);
    }

#pragma unroll
    for (int i = 0; i < 2; ++i)
#pragma unroll
        for (int j = 0; j < 2; ++j) {
            int n = cb + j * 16 + l15;
            float b1 = eb1[n];
#pragma unroll
            for (int v = 0; v < 4; ++v) {
                int m = rb + i * 16 + l4 * 4 + v;
                float val = acc[i][j][v] + b1
                          + bf2f(PQs[m * LDK2 + n]) + bf2f(PQs[m * LDK2 + 128 + n]);
                Hs[m * LDK + n] = f2bf(fmaxf(val, 0.f));
            }
        }
    __syncthreads();

    f32x4 acc2[2][2] = {};
#pragma unroll
    for (int k0 = 0; k0 < 128; k0 += 32) {
        bf16x8 a[2], b[2];
#pragma unroll
        for (int f = 0; f < 2; ++f) {
            a[f] = *(const bf16x8*)(Hs + (rb + f * 16 + l15) * LDK + k0 + l4 * 8);
            b[f] = *(const bf16x8*)(W2s + (cb + f * 16 + l15) * LDK + k0 + l4 * 8);
        }
#pragma unroll
        for (int i = 0; i < 2; ++i)
#pragma unroll
            for (int j = 0; j < 2; ++j)
                acc2[i][j] = MFMA16(a[i], b[j], acc2[i][j]);
    }

#pragma unroll
    for (int i = 0; i < 2; ++i)
#pragma unroll
        for (int j = 0; j < 2; ++j) {
            int n = cb + j * 16 + l15;
            float b2 = eb2[n];
#pragma unroll
            for (int v = 0; v < 4; ++v) {
                int m = rb + i * 16 + l4 * 4 + v;
                if (m < nvalid) {
                    float upd = acc2[i][j][v] + b2;
                    size_t off = (size_t)(e0 + m) * 128 + n;
                    edges_out[off] = edges[off] + mult * upd;   // fp32 residual
                    unsafeAtomicAdd(adj + (size_t)Rs[m] * 128 + n, upd);
                }
            }
        }
}

// ---------------------------------------------------------------------------
// node_mlp: h = relu([nodes|adj]@nW1 + nb1) ; upd = h@nW2 + nb2
// nodes_out = nodes + mult*upd
// ---------------------------------------------------------------------------
__global__ __launch_bounds__(512)
void node_mlp(const float* __restrict__ nodes, const float* __restrict__ adj,
              const u16* __restrict__ W1t,   // [128][256]
              const u16* __restrict__ W2t,   // [128][128]
              const float* __restrict__ nb1, const float* __restrict__ nb2,
              const float* __restrict__ rm_w, float* __restrict__ nodes_out) {
    __shared__ u16 Xs[64 * LDK2];
    __shared__ u16 W1s[128 * LDK2];
    __shared__ u16 W2s[128 * LDK];
    __shared__ u16 Hs[64 * LDK];

    const int tid = threadIdx.x;
    const int n0 = blockIdx.x * 64;
    const int nvalid = min(64, NN - n0);
    const float mult = log1pf(expf(rm_w[0]));

    for (int idx = tid; idx < 64 * 64; idx += 512) {   // [nodes | adj] -> bf16
        int row = idx >> 6, c4 = idx & 63;
        int nd = n0 + row; if (nd >= NN) nd = NN - 1;
        const float* src = (c4 < 32) ? (nodes + (size_t)nd * 128 + c4 * 4)
                                     : (adj + (size_t)nd * 128 + (c4 - 32) * 4);
        float4 v = *(const float4*)src;
        ushort4 u; u.x = f2bf(v.x); u.y = f2bf(v.y); u.z = f2bf(v.z); u.w = f2bf(v.w);
        *(ushort4*)(Xs + row * LDK2 + c4 * 4) = u;
    }
    for (int idx = tid; idx < 128 * 32; idx += 512) {
        int row = idx >> 5, c = idx & 31;
        *(int4*)(W1s + row * LDK2 + c * 8) = *(const int4*)(W1t + row * 256 + c * 8);
    }
    for (int idx = tid; idx < 128 * 16; idx += 512) {
        int row = idx >> 4, c = idx & 15;
        *(int4*)(W2s + row * LDK + c * 8) = *(const int4*)(W2t + row * 128 + c * 8);
    }
    __syncthreads();

    const int lane = tid & 63;
    const int w = tid >> 6;
    const int rb = (w >> 2) * 32, cb = (w & 3) * 32;
    const int l15 = lane & 15, l4 = lane >> 4;

    f32x4 acc[2][2] = {};
#pragma unroll
    for (int k0 = 0; k0 < 256; k0 += 32) {
        bf16x8 a[2], b[2];
#pragma unroll
        for (int f = 0; f < 2; ++f) {
            a[f] = *(const bf16x8*)(Xs + (rb + f * 16 + l15) * LDK2 + k0 + l4 * 8);
            b[f] = *(const bf16x8*)(W1s + (cb + f * 16 + l15) * LDK2 + k0 + l4 * 8);
        }
#pragma unroll
        for (int i = 0; i < 2; ++i)
#pragma unroll
            for (int j = 0; j < 2; ++j)
                acc[i][j] = MFMA16(a[i], b[j], acc[i][j]);
    }

#pragma unroll
    for (int i = 0; i < 2; ++i)
#pragma unroll
        for (int j = 0; j < 2; ++j) {
            int n = cb + j * 16 + l15;
            float b1 = nb1[n];
#pragma unroll
            for (int v = 0; v < 4; ++v) {
                int m = rb + i * 16 + l4 * 4 + v;
                Hs[m * LDK + n] = f2bf(fmaxf(acc[i][j][v] + b1, 0.f));
            }
        }
    __syncthreads();

    f32x4 acc2[2][2] = {};
#pragma unroll
    for (int k0 = 0; k0 < 128; k0 += 32) {
        bf16x8 a[2], b[2];
#pragma unroll
        for (int f = 0; f < 2; ++f) {
            a[f] = *(const bf16x8*)(Hs + (rb + f * 16 + l15) * LDK + k0 + l4 * 8);
            b[f] = *(const bf16x8*)(W2s + (cb + f * 16 + l15) * LDK + k0 + l4 * 8);
        }
#pragma unroll
        for (int i = 0; i < 2; ++i)
#pragma unroll
            for (int j = 0; j < 2; ++j)
                acc2[i][j] = MFMA16(a[i], b[j], acc2[i][j]);
    }

#pragma unroll
    for (int i = 0; i < 2; ++i)
#pragma unroll
        for (int j = 0; j < 2; ++j) {
            int n = cb + j * 16 + l15;
            float b2 = nb2[n];
#pragma unroll
            for (int v = 0; v < 4; ++v) {
                int m = rb + i * 16 + l4 * 4 + v;
                if (m < nvalid) {
                    size_t off = (size_t)(n0 + m) * 128 + n;
                    nodes_out[off] = nodes[off] + mult * (acc2[i][j][v] + b2);
                }
            }
        }
}

// ---------------------------------------------------------------------------
extern "C" void kernel_launch(void* const* d_in, const int* in_sizes, int n_in,
                              void* d_out, int out_size, void* d_ws, size_t ws_size,
                              hipStream_t stream) {
    const float* nodes     = (const float*)d_in[0];
    const float* edges     = (const float*)d_in[1];
    const int*   receivers = (const int*)d_in[2];
    const int*   senders   = (const int*)d_in[3];
    // d_in[4] global_latent: unused by the reference
    const float* eW1  = (const float*)d_in[5];
    const float* eb1  = (const float*)d_in[6];
    const float* eW2  = (const float*)d_in[7];
    const float* eb2  = (const float*)d_in[8];
    const float* nW1  = (const float*)d_in[9];
    const float* nb1  = (const float*)d_in[10];
    const float* nW2  = (const float*)d_in[11];
    const float* nb2  = (const float*)d_in[12];
    const float* rm_w = (const float*)d_in[13];

    char* ws = (char*)d_ws;
    u16*   PQw  = (u16*)(ws + 0);           // [N][256] bf16 : 25,600,000 B
    float* adj  = (float*)(ws + 25600000);  // [N][128] f32  : 25,600,000 B
    u16*   W1at = (u16*)(ws + 51200000);    // 32 KB
    u16*   eW2t = (u16*)(ws + 51232768);    // 32 KB
    u16*   Wbct = (u16*)(ws + 51265536);    // 64 KB
    u16*   nW1t = (u16*)(ws + 51331072);    // 64 KB
    u16*   nW2t = (u16*)(ws + 51396608);    // 32 KB

    float* nodes_out = (float*)d_out;
    float* edges_out = (float*)d_out + (size_t)NN * 128;

    hipMemsetAsync(adj, 0, (size_t)NN * 128 * sizeof(float), stream);
    prep_w<<<448, 256, 0, stream>>>(eW1, eW2, nW1, nW2, W1at, eW2t, Wbct, nW1t, nW2t);
    node_pq<<<(NN + 63) / 64, 512, 0, stream>>>(nodes, Wbct, PQw);
    edge_mlp<<<(NE + 63) / 64, 512, 0, stream>>>(edges, receivers, senders, PQw, W1at, eW2t,
                                                 eb1, eb2, rm_w, edges_out, adj);
    node_mlp<<<(NN + 63) / 64, 512, 0, stream>>>(nodes, adj, nW1t, nW2t, nb1, nb2, rm_w,
                                                 nodes_out);
}

// Round 5
// 784.918 us; speedup vs baseline: 1.1695x; 1.1695x over previous
//
#include <hip/hip_runtime.h>
#include <hip/hip_bf16.h>

#define NN 50000
#define NE 500000

typedef __attribute__((ext_vector_type(4))) float f32x4;
typedef __attribute__((ext_vector_type(8))) short bf16x8;
typedef unsigned short u16;

#define LDK 136    // 128 + 8 pad, u16 units
#define LDK2 264   // 256 + 8 pad

#define MFMA16(a, b, c) __builtin_amdgcn_mfma_f32_16x16x32_bf16((a), (b), (c), 0, 0, 0)

__device__ __forceinline__ float bf2f(u16 u) {
    union { unsigned int i; float f; } v; v.i = ((unsigned int)u) << 16; return v.f;
}
__device__ __forceinline__ u16 f2bf(float f) {
    union { float f; unsigned int i; } v; v.f = f;
    return (u16)((v.i + 0x7fffu + ((v.i >> 16) & 1u)) >> 16);  // RTNE
}

// ---------------------------------------------------------------------------
// prep: transpose + bf16-convert all weight blocks into ws
// ---------------------------------------------------------------------------
__global__ void prep_w(const float* __restrict__ eW1, const float* __restrict__ eW2,
                       const float* __restrict__ nW1, const float* __restrict__ nW2,
                       u16* __restrict__ W1at, u16* __restrict__ eW2t, u16* __restrict__ Wbct,
                       u16* __restrict__ nW1t, u16* __restrict__ nW2t) {
    int idx = blockIdx.x * blockDim.x + threadIdx.x;
    if (idx < 16384) { int j = idx >> 7, k = idx & 127; W1at[j * 128 + k] = f2bf(eW1[k * 128 + j]); return; }
    idx -= 16384;
    if (idx < 16384) { int j = idx >> 7, k = idx & 127; eW2t[j * 128 + k] = f2bf(eW2[k * 128 + j]); return; }
    idx -= 16384;
    if (idx < 32768) {
        int j = idx >> 7, k = idx & 127;
        float v = (j < 128) ? eW1[(128 + k) * 128 + j] : eW1[(256 + k) * 128 + (j - 128)];
        Wbct[j * 128 + k] = f2bf(v); return;
    }
    idx -= 32768;
    if (idx < 32768) { int j = idx >> 8, k = idx & 255; nW1t[j * 256 + k] = f2bf(nW1[k * 128 + j]); return; }
    idx -= 32768;
    if (idx < 16384) { int j = idx >> 7, k = idx & 127; nW2t[j * 128 + k] = f2bf(nW2[k * 128 + j]); return; }
}

// ---------------------------------------------------------------------------
// node_pq: PQw[n][0:256] = nodes[n] @ [W1b|W1c]  (bf16 out)
// 64-node tiles, 8 waves; wave w owns output cols [w*32, w*32+32), weights in regs.
// ---------------------------------------------------------------------------
__global__ __launch_bounds__(512, 4)
void node_pq(const float* __restrict__ nodes, const u16* __restrict__ Wbct,
             u16* __restrict__ PQw) {
    __shared__ u16 Xs[64 * LDK];
    const int tid = threadIdx.x;
    const int lane = tid & 63;
    const int w = tid >> 6;
    const int l15 = lane & 15, l4 = lane >> 4;
    const int cb = w * 32;
    const int n0 = blockIdx.x * 64;
    const int nvalid = min(64, NN - n0);

    bf16x8 bw[2][4];
#pragma unroll
    for (int kk = 0; kk < 4; ++kk)
#pragma unroll
        for (int j = 0; j < 2; ++j)
            bw[j][kk] = *(const bf16x8*)(Wbct + (cb + j * 16 + l15) * 128 + kk * 32 + l4 * 8);

    for (int idx = tid; idx < 64 * 32; idx += 512) {
        int row = idx >> 5, c4 = idx & 31;
        int nd = n0 + row; if (nd >= NN) nd = NN - 1;
        float4 v = *(const float4*)(nodes + (size_t)nd * 128 + c4 * 4);
        ushort4 u; u.x = f2bf(v.x); u.y = f2bf(v.y); u.z = f2bf(v.z); u.w = f2bf(v.w);
        *(ushort4*)(Xs + row * LDK + c4 * 4) = u;
    }
    __syncthreads();

    f32x4 acc[4][2] = {};
#pragma unroll
    for (int kk = 0; kk < 4; ++kk) {
#pragma unroll
        for (int f = 0; f < 4; ++f) {
            bf16x8 a = *(const bf16x8*)(Xs + (f * 16 + l15) * LDK + kk * 32 + l4 * 8);
#pragma unroll
            for (int j = 0; j < 2; ++j)
                acc[f][j] = MFMA16(a, bw[j][kk], acc[f][j]);
        }
    }
#pragma unroll
    for (int i = 0; i < 4; ++i)
#pragma unroll
        for (int j = 0; j < 2; ++j) {
            int n = cb + j * 16 + l15;
#pragma unroll
            for (int v = 0; v < 4; ++v) {
                int m = i * 16 + l4 * 4 + v;
                if (m < nvalid) PQw[(size_t)(n0 + m) * 256 + n] = f2bf(acc[i][j][v]);
            }
        }
}

// ---------------------------------------------------------------------------
// edge_mlp: fused edge MLP + residual + atomic scatter.
// 64-edge tiles, 8 waves; wave w owns output cols [w*16, w*16+16), weights in regs.
// LDS = Xs + PQs + Hs + Rs ~ 67 KB -> 2 blocks/CU.
// ---------------------------------------------------------------------------
__global__ __launch_bounds__(512, 4)
void edge_mlp(const float* __restrict__ edges,
              const int* __restrict__ recv, const int* __restrict__ send,
              const u16* __restrict__ PQw,
              const u16* __restrict__ W1at, const u16* __restrict__ W2t,
              const float* __restrict__ eb1, const float* __restrict__ eb2,
              const float* __restrict__ rm_w,
              float* __restrict__ edges_out, float* __restrict__ adj) {
    __shared__ u16 Xs[64 * LDK];
    __shared__ u16 PQs[64 * LDK2];
    __shared__ u16 Hs[64 * LDK];
    __shared__ int Rs[64];

    const int tid = threadIdx.x;
    const int lane = tid & 63;
    const int w = tid >> 6;
    const int l15 = lane & 15, l4 = lane >> 4;
    const int cb = w * 16;
    const int e0 = blockIdx.x * 64;
    const int nvalid = min(64, NE - e0);
    const float mult = log1pf(expf(rm_w[0]));

    // per-wave weight slices in registers (L2-resident global reads)
    bf16x8 bw1[4], bw2[4];
#pragma unroll
    for (int kk = 0; kk < 4; ++kk) {
        bw1[kk] = *(const bf16x8*)(W1at + (cb + l15) * 128 + kk * 32 + l4 * 8);
        bw2[kk] = *(const bf16x8*)(W2t + (cb + l15) * 128 + kk * 32 + l4 * 8);
    }

    for (int idx = tid; idx < 64 * 32; idx += 512) {   // edges tile fp32->bf16
        int row = idx >> 5, c4 = idx & 31;
        int e = e0 + row; if (e >= NE) e = NE - 1;
        float4 v = *(const float4*)(edges + (size_t)e * 128 + c4 * 4);
        ushort4 u; u.x = f2bf(v.x); u.y = f2bf(v.y); u.z = f2bf(v.z); u.w = f2bf(v.w);
        *(ushort4*)(Xs + row * LDK + c4 * 4) = u;
    }
    if (tid < 64) {
        int e = e0 + tid; if (e >= NE) e = NE - 1;
        Rs[tid] = recv[e];
    }
    for (int idx = tid; idx < 64 * 32; idx += 512) {   // gather P[send] | Q[recv]
        int row = idx >> 5, half = (idx >> 4) & 1, c = idx & 15;
        int e = e0 + row; if (e >= NE) e = NE - 1;
        int node = half ? recv[e] : send[e];
        int4 v = *(const int4*)(PQw + (size_t)node * 256 + half * 128 + c * 8);
        *(int4*)(PQs + row * LDK2 + half * 128 + c * 8) = v;
    }
    __syncthreads();

    f32x4 acc[4] = {};
#pragma unroll
    for (int kk = 0; kk < 4; ++kk) {
#pragma unroll
        for (int f = 0; f < 4; ++f) {
            bf16x8 a = *(const bf16x8*)(Xs + (f * 16 + l15) * LDK + kk * 32 + l4 * 8);
            acc[f] = MFMA16(a, bw1[kk], acc[f]);
        }
    }

    {
        const int n = cb + l15;
        const float b1 = eb1[n];
#pragma unroll
        for (int i = 0; i < 4; ++i)
#pragma unroll
            for (int v = 0; v < 4; ++v) {
                int m = i * 16 + l4 * 4 + v;
                float val = acc[i][v] + b1
                          + bf2f(PQs[m * LDK2 + n]) + bf2f(PQs[m * LDK2 + 128 + n]);
                Hs[m * LDK + n] = f2bf(fmaxf(val, 0.f));
            }
    }
    __syncthreads();

    f32x4 acc2[4] = {};
#pragma unroll
    for (int kk = 0; kk < 4; ++kk) {
#pragma unroll
        for (int f = 0; f < 4; ++f) {
            bf16x8 a = *(const bf16x8*)(Hs + (f * 16 + l15) * LDK + kk * 32 + l4 * 8);
            acc2[f] = MFMA16(a, bw2[kk], acc2[f]);
        }
    }

    {
        const int n = cb + l15;
        const float b2 = eb2[n];
#pragma unroll
        for (int i = 0; i < 4; ++i)
#pragma unroll
            for (int v = 0; v < 4; ++v) {
                int m = i * 16 + l4 * 4 + v;
                if (m < nvalid) {
                    float upd = acc2[i][v] + b2;
                    size_t off = (size_t)(e0 + m) * 128 + n;
                    edges_out[off] = edges[off] + mult * upd;
                    unsafeAtomicAdd(adj + (size_t)Rs[m] * 128 + n, upd);
                }
            }
    }
}

// ---------------------------------------------------------------------------
// node_mlp: h = relu([nodes|adj]@nW1 + nb1) ; nodes_out = nodes + mult*(h@nW2 + nb2)
// 64-node tiles, 8 waves; wave owns 16 cols, weights in regs. LDS ~ 51 KB.
// ---------------------------------------------------------------------------
__global__ __launch_bounds__(512, 4)
void node_mlp(const float* __restrict__ nodes, const float* __restrict__ adj,
              const u16* __restrict__ W1t,   // [128][256]
              const u16* __restrict__ W2t,   // [128][128]
              const float* __restrict__ nb1, const float* __restrict__ nb2,
              const float* __restrict__ rm_w, float* __restrict__ nodes_out) {
    __shared__ u16 Xs[64 * LDK2];
    __shared__ u16 Hs[64 * LDK];

    const int tid = threadIdx.x;
    const int lane = tid & 63;
    const int w = tid >> 6;
    const int l15 = lane & 15, l4 = lane >> 4;
    const int cb = w * 16;
    const int n0 = blockIdx.x * 64;
    const int nvalid = min(64, NN - n0);
    const float mult = log1pf(expf(rm_w[0]));

    bf16x8 bw1[8], bw2[4];
#pragma unroll
    for (int kk = 0; kk < 8; ++kk)
        bw1[kk] = *(const bf16x8*)(W1t + (cb + l15) * 256 + kk * 32 + l4 * 8);
#pragma unroll
    for (int kk = 0; kk < 4; ++kk)
        bw2[kk] = *(const bf16x8*)(W2t + (cb + l15) * 128 + kk * 32 + l4 * 8);

    for (int idx = tid; idx < 64 * 64; idx += 512) {   // [nodes | adj] -> bf16
        int row = idx >> 6, c4 = idx & 63;
        int nd = n0 + row; if (nd >= NN) nd = NN - 1;
        const float* src = (c4 < 32) ? (nodes + (size_t)nd * 128 + c4 * 4)
                                     : (adj + (size_t)nd * 128 + (c4 - 32) * 4);
        float4 v = *(const float4*)src;
        ushort4 u; u.x = f2bf(v.x); u.y = f2bf(v.y); u.z = f2bf(v.z); u.w = f2bf(v.w);
        *(ushort4*)(Xs + row * LDK2 + c4 * 4) = u;
    }
    __syncthreads();

    f32x4 acc[4] = {};
#pragma unroll
    for (int kk = 0; kk < 8; ++kk) {
#pragma unroll
        for (int f = 0; f < 4; ++f) {
            bf16x8 a = *(const bf16x8*)(Xs + (f * 16 + l15) * LDK2 + kk * 32 + l4 * 8);
            acc[f] = MFMA16(a, bw1[kk], acc[f]);
        }
    }

    {
        const int n = cb + l15;
        const float b1 = nb1[n];
#pragma unroll
        for (int i = 0; i < 4; ++i)
#pragma unroll
            for (int v = 0; v < 4; ++v) {
                int m = i * 16 + l4 * 4 + v;
                Hs[m * LDK + n] = f2bf(fmaxf(acc[i][v] + b1, 0.f));
            }
    }
    __syncthreads();

    f32x4 acc2[4] = {};
#pragma unroll
    for (int kk = 0; kk < 4; ++kk) {
#pragma unroll
        for (int f = 0; f < 4; ++f) {
            bf16x8 a = *(const bf16x8*)(Hs + (f * 16 + l15) * LDK + kk * 32 + l4 * 8);
            acc2[f] = MFMA16(a, bw2[kk], acc2[f]);
        }
    }

    {
        const int n = cb + l15;
        const float b2 = nb2[n];
#pragma unroll
        for (int i = 0; i < 4; ++i)
#pragma unroll
            for (int v = 0; v < 4; ++v) {
                int m = i * 16 + l4 * 4 + v;
                if (m < nvalid) {
                    size_t off = (size_t)(n0 + m) * 128 + n;
                    nodes_out[off] = nodes[off] + mult * (acc2[i][v] + b2);
                }
            }
    }
}

// ---------------------------------------------------------------------------
extern "C" void kernel_launch(void* const* d_in, const int* in_sizes, int n_in,
                              void* d_out, int out_size, void* d_ws, size_t ws_size,
                              hipStream_t stream) {
    const float* nodes     = (const float*)d_in[0];
    const float* edges     = (const float*)d_in[1];
    const int*   receivers = (const int*)d_in[2];
    const int*   senders   = (const int*)d_in[3];
    const float* eW1  = (const float*)d_in[5];
    const float* eb1  = (const float*)d_in[6];
    const float* eW2  = (const float*)d_in[7];
    const float* eb2  = (const float*)d_in[8];
    const float* nW1  = (const float*)d_in[9];
    const float* nb1  = (const float*)d_in[10];
    const float* nW2  = (const float*)d_in[11];
    const float* nb2  = (const float*)d_in[12];
    const float* rm_w = (const float*)d_in[13];

    char* ws = (char*)d_ws;
    u16*   PQw  = (u16*)(ws + 0);           // [N][256] bf16
    float* adj  = (float*)(ws + 25600000);  // [N][128] f32
    u16*   W1at = (u16*)(ws + 51200000);
    u16*   eW2t = (u16*)(ws + 51232768);
    u16*   Wbct = (u16*)(ws + 51265536);
    u16*   nW1t = (u16*)(ws + 51331072);
    u16*   nW2t = (u16*)(ws + 51396608);

    float* nodes_out = (float*)d_out;
    float* edges_out = (float*)d_out + (size_t)NN * 128;

    hipMemsetAsync(adj, 0, (size_t)NN * 128 * sizeof(float), stream);
    prep_w<<<448, 256, 0, stream>>>(eW1, eW2, nW1, nW2, W1at, eW2t, Wbct, nW1t, nW2t);
    node_pq<<<(NN + 63) / 64, 512, 0, stream>>>(nodes, Wbct, PQw);
    edge_mlp<<<(NE + 63) / 64, 512, 0, stream>>>(edges, receivers, senders, PQw, W1at, eW2t,
                                                 eb1, eb2, rm_w, edges_out, adj);
    node_mlp<<<(NN + 63) / 64, 512, 0, stream>>>(nodes, adj, nW1t, nW2t, nb1, nb2, rm_w,
                                                 nodes_out);
}